// Round 3
// baseline (683.811 us; speedup 1.0000x reference)
//
#include <hip/hip_runtime.h>

#define NF     128
#define BATCH  64
#define NNODES 4096
#define MROWS  (BATCH * NNODES)       // 262144
#define NEDGE  (BATCH * (NNODES - 1)) // 262080
#define LN_EPS 1e-5f
#define AP     136                    // padded row stride (shorts) for W^T / out-repack

typedef short  short8  __attribute__((ext_vector_type(8)));
typedef float  float4v __attribute__((ext_vector_type(4)));

__device__ __forceinline__ unsigned short f2bf(float f) {
    union { float f; unsigned u; } v; v.f = f;
    unsigned r = v.u;
    r = r + 0x7FFF + ((r >> 16) & 1);   // RNE
    return (unsigned short)(r >> 16);
}
__device__ __forceinline__ float bf2f(unsigned short b) {
    union { unsigned u; float f; } v; v.u = ((unsigned)b) << 16;
    return v.f;
}

// Stage a 128x128 fp32 weight (k-major) into Wt as bf16 n-major, padded.
__device__ __forceinline__ void stage_w(const float* __restrict__ W,
                                        unsigned short* __restrict__ Wt, int tid) {
    #pragma unroll
    for (int i = 0; i < 16; ++i) {
        int flat = tid + 256 * i;          // 0..4095
        int k    = flat >> 5;              // 0..127
        int n0   = (flat & 31) * 4;
        float4v wv = *(const float4v*)(W + k * NF + n0);
        Wt[(n0 + 0) * AP + k] = f2bf(wv[0]);
        Wt[(n0 + 1) * AP + k] = f2bf(wv[1]);
        Wt[(n0 + 2) * AP + k] = f2bf(wv[2]);
        Wt[(n0 + 3) * AP + k] = f2bf(wv[3]);
    }
}

// In-place bias + LayerNorm(128) + ELU on the C-layout accumulator.
// acc[c][r] holds (row = qu*4+r, col = c*16+lnm); row's 128 cols live in the
// 16 lanes of this lane's 16-group (lane = qu*16+lnm) -> shfl_xor width 16.
__device__ __forceinline__ void ln_elu(float4v acc[8], const float* __restrict__ P,
                                       int lnm) {
    float bias[8], gn[8], bt[8];
    #pragma unroll
    for (int c = 0; c < 8; ++c) {
        int n = c * 16 + lnm;
        bias[c] = P[n]; gn[c] = P[NF + n]; bt[c] = P[2 * NF + n];
    }
    #pragma unroll
    for (int r = 0; r < 4; ++r) {
        float s1 = 0.f, s2 = 0.f;
        #pragma unroll
        for (int c = 0; c < 8; ++c) {
            float t = acc[c][r] + bias[c];
            acc[c][r] = t;
            s1 += t; s2 += t * t;
        }
        #pragma unroll
        for (int m = 1; m < 16; m <<= 1) {
            s1 += __shfl_xor(s1, m, 16);
            s2 += __shfl_xor(s2, m, 16);
        }
        float mu  = s1 * (1.0f / 128.0f);
        float var = s2 * (1.0f / 128.0f) - mu * mu;
        float rs  = rsqrtf(var + LN_EPS);
        #pragma unroll
        for (int c = 0; c < 8; ++c) {
            float y = (acc[c][r] - mu) * rs * gn[c] + bt[c];
            acc[c][r] = (y > 0.f) ? y : (__expf(y) - 1.0f);
        }
    }
}

// Fused layer1+layer2: x (fp32) -> LN/ELU(xW1) -> LN/ELU(h1 W2) -> h2 (bf16).
// Each WAVE independently processes 16-row strips; no barriers in main loop.
__global__ __launch_bounds__(256, 3)
void fused12_kernel(const float* __restrict__ x,
                    const float* __restrict__ W1, const float* __restrict__ b1,
                    const float* __restrict__ g1, const float* __restrict__ be1,
                    const float* __restrict__ W2, const float* __restrict__ b2,
                    const float* __restrict__ g2, const float* __restrict__ be2,
                    unsigned short* __restrict__ h2out)
{
    __shared__ unsigned short Wt[NF * AP];   // 34816 B; reused as per-wave frag bufs
    __shared__ float P[6 * NF];              // b1,g1,be1 | b2,g2,be2

    const int tid  = threadIdx.x;
    const int lane = tid & 63;
    const int wave = tid >> 6;
    const int lnm  = lane & 15;
    const int qu   = lane >> 4;

    // ---- setup: both weight fragment sets into registers ----
    stage_w(W1, Wt, tid);
    if (tid < NF) {
        P[tid]          = b1[tid];  P[NF + tid]     = g1[tid];  P[2 * NF + tid] = be1[tid];
        P[3 * NF + tid] = b2[tid];  P[4 * NF + tid] = g2[tid];  P[5 * NF + tid] = be2[tid];
    }
    __syncthreads();
    short8 bf1[8][4];
    #pragma unroll
    for (int c = 0; c < 8; ++c)
        #pragma unroll
        for (int s = 0; s < 4; ++s)
            bf1[c][s] = *(const short8*)&Wt[(c * 16 + lnm) * AP + s * 32 + qu * 8];
    __syncthreads();
    stage_w(W2, Wt, tid);
    __syncthreads();
    short8 bf2[8][4];
    #pragma unroll
    for (int c = 0; c < 8; ++c)
        #pragma unroll
        for (int s = 0; s < 4; ++s)
            bf2[c][s] = *(const short8*)&Wt[(c * 16 + lnm) * AP + s * 32 + qu * 8];
    __syncthreads();

    // per-wave buffer: 2176 shorts (frag layout uses 2048; out-repack uses 16*AP)
    unsigned short* myFrag = &Wt[wave * 2176];

    const int nstrips = MROWS / 16;          // 16384
    for (int strip = blockIdx.x * 4 + wave; strip < nstrips; strip += gridDim.x * 4) {
        const size_t rowBase = (size_t)strip * 16;

        // ---- stage x strip: lane covers (row=lnm, k-quarter=qu) ----
        const float* xs = x + (rowBase + lnm) * NF + qu * 32;
        #pragma unroll
        for (int qq = 0; qq < 4; ++qq) {
            float4v a = *(const float4v*)(xs + qq * 8);
            float4v b = *(const float4v*)(xs + qq * 8 + 4);
            union { short8 v; unsigned short e[8]; } u;
            u.e[0] = f2bf(a[0]); u.e[1] = f2bf(a[1]); u.e[2] = f2bf(a[2]); u.e[3] = f2bf(a[3]);
            u.e[4] = f2bf(b[0]); u.e[5] = f2bf(b[1]); u.e[6] = f2bf(b[2]); u.e[7] = f2bf(b[3]);
            // slot (s=qu, quad=qq, m=lnm): holds A[m][s*32+quad*8+j]
            *(short8*)&myFrag[(((qu * 4 + qq) * 16) + lnm) * 8] = u.v;
        }

        // ---- layer 1 MFMA ----
        float4v acc[8];
        #pragma unroll
        for (int c = 0; c < 8; ++c) acc[c] = (float4v){0.f, 0.f, 0.f, 0.f};
        #pragma unroll
        for (int s = 0; s < 4; ++s) {
            short8 af = *(const short8*)&myFrag[((s * 4 + qu) * 16 + lnm) * 8];
            #pragma unroll
            for (int c = 0; c < 8; ++c)
                acc[c] = __builtin_amdgcn_mfma_f32_16x16x32_bf16(af, bf1[c][s], acc[c], 0, 0, 0);
        }
        ln_elu(acc, &P[0], lnm);

        // ---- repack h1 into A-fragment layout for layer 2 (in-wave) ----
        // value (m = qu*4+r, k = c*16+lnm) -> slot (k>>3)*16+m, byte j = k&7
        #pragma unroll
        for (int c = 0; c < 8; ++c)
            #pragma unroll
            for (int r = 0; r < 4; ++r)
                myFrag[((c * 2 + (lnm >> 3)) * 16 + qu * 4 + r) * 8 + (lnm & 7)] = f2bf(acc[c][r]);

        // ---- layer 2 MFMA ----
        #pragma unroll
        for (int c = 0; c < 8; ++c) acc[c] = (float4v){0.f, 0.f, 0.f, 0.f};
        #pragma unroll
        for (int s = 0; s < 4; ++s) {
            short8 af = *(const short8*)&myFrag[((s * 4 + qu) * 16 + lnm) * 8];
            #pragma unroll
            for (int c = 0; c < 8; ++c)
                acc[c] = __builtin_amdgcn_mfma_f32_16x16x32_bf16(af, bf2[c][s], acc[c], 0, 0, 0);
        }
        ln_elu(acc, &P[3 * NF], lnm);

        // ---- out-repack (padded row-major) + 16B vector stores ----
        #pragma unroll
        for (int c = 0; c < 8; ++c)
            #pragma unroll
            for (int r = 0; r < 4; ++r)
                myFrag[(qu * 4 + r) * AP + c * 16 + lnm] = f2bf(acc[c][r]);

        const int rr = lane >> 2, kc = lane & 3;
        unsigned short* orow = h2out + (rowBase + rr) * NF + kc * 32;
        #pragma unroll
        for (int t = 0; t < 4; ++t)
            *(short8*)(orow + t * 8) = *(const short8*)&myFrag[rr * AP + kc * 32 + t * 8];
    }
}

// Edge kernel: e = max(h2[child], h2[parent]) -> LN/ELU(e Wr1) -> dot Wr2 + br2.
__global__ __launch_bounds__(256, 3)
void edge_kernel(const unsigned short* __restrict__ h2,
                 const int* __restrict__ pidx,
                 const float* __restrict__ Wr1, const float* __restrict__ br1,
                 const float* __restrict__ gr1, const float* __restrict__ ber1,
                 const float* __restrict__ Wr2, const float* __restrict__ br2,
                 float* __restrict__ rout)
{
    __shared__ unsigned short Wt[NF * AP];
    __shared__ float P[4 * NF];              // br1,gr1,ber1 | Wr2

    const int tid  = threadIdx.x;
    const int lane = tid & 63;
    const int wave = tid >> 6;
    const int lnm  = lane & 15;
    const int qu   = lane >> 4;

    stage_w(Wr1, Wt, tid);
    if (tid < NF) {
        P[tid]          = br1[tid]; P[NF + tid] = gr1[tid];
        P[2 * NF + tid] = ber1[tid]; P[3 * NF + tid] = Wr2[tid];
    }
    __syncthreads();
    short8 bfr[8][4];
    #pragma unroll
    for (int c = 0; c < 8; ++c)
        #pragma unroll
        for (int s = 0; s < 4; ++s)
            bfr[c][s] = *(const short8*)&Wt[(c * 16 + lnm) * AP + s * 32 + qu * 8];
    __syncthreads();

    unsigned short* myFrag = &Wt[wave * 2176];
    const float br2v = br2[0];

    const int nstrips = NEDGE / 16;          // 16380
    for (int strip = blockIdx.x * 4 + wave; strip < nstrips; strip += gridDim.x * 4) {
        // ---- gather + max stage: lane covers (edge=lnm-th of strip, quarter=qu) ----
        int e = strip * 16 + lnm;
        unsigned bb = (unsigned)e / 4095u;
        int crow = e + (int)bb;              // child row in h2
        int prow = pidx[e];
        const unsigned short* cs = h2 + (size_t)crow * NF + qu * 32;
        const unsigned short* ps = h2 + (size_t)prow * NF + qu * 32;
        #pragma unroll
        for (int qq = 0; qq < 4; ++qq) {
            short8 cv = *(const short8*)(cs + qq * 8);
            short8 pv = *(const short8*)(ps + qq * 8);
            union { short8 v; unsigned short e8[8]; } u;
            #pragma unroll
            for (int j = 0; j < 8; ++j)
                u.e8[j] = f2bf(fmaxf(bf2f((unsigned short)cv[j]), bf2f((unsigned short)pv[j])));
            *(short8*)&myFrag[(((qu * 4 + qq) * 16) + lnm) * 8] = u.v;
        }

        float4v acc[8];
        #pragma unroll
        for (int c = 0; c < 8; ++c) acc[c] = (float4v){0.f, 0.f, 0.f, 0.f};
        #pragma unroll
        for (int s = 0; s < 4; ++s) {
            short8 af = *(const short8*)&myFrag[((s * 4 + qu) * 16 + lnm) * 8];
            #pragma unroll
            for (int c = 0; c < 8; ++c)
                acc[c] = __builtin_amdgcn_mfma_f32_16x16x32_bf16(af, bfr[c][s], acc[c], 0, 0, 0);
        }
        ln_elu(acc, &P[0], lnm);

        float w2c[8];
        #pragma unroll
        for (int c = 0; c < 8; ++c) w2c[c] = P[3 * NF + c * 16 + lnm];
        #pragma unroll
        for (int r = 0; r < 4; ++r) {
            float t = 0.f;
            #pragma unroll
            for (int c = 0; c < 8; ++c) t += acc[c][r] * w2c[c];
            #pragma unroll
            for (int m = 1; m < 16; m <<= 1) t += __shfl_xor(t, m, 16);
            if (lnm == 0) rout[strip * 16 + qu * 4 + r] = t + br2v;
        }
    }
}

__global__ __launch_bounds__(256)
void lse_kernel(const float* __restrict__ r, float* __restrict__ out)
{
    __shared__ float red[256];
    const int b = blockIdx.x;
    const float* rb = r + (size_t)b * 4095;

    float mx = -1e30f;
    for (int i = threadIdx.x; i < 4095; i += 256) mx = fmaxf(mx, rb[i]);
    red[threadIdx.x] = mx;
    __syncthreads();
    for (int s = 128; s > 0; s >>= 1) {
        if (threadIdx.x < s) red[threadIdx.x] = fmaxf(red[threadIdx.x], red[threadIdx.x + s]);
        __syncthreads();
    }
    mx = red[0];
    __syncthreads();

    float sum = 0.f;
    for (int i = threadIdx.x; i < 4095; i += 256) sum += __expf(rb[i] - mx);
    red[threadIdx.x] = sum;
    __syncthreads();
    for (int s = 128; s > 0; s >>= 1) {
        if (threadIdx.x < s) red[threadIdx.x] += red[threadIdx.x + s];
        __syncthreads();
    }
    float lse = mx + __logf(red[0]);

    for (int i = threadIdx.x; i < 4095; i += 256)
        out[(size_t)b * 4095 + i] = rb[i] - lse;
}

extern "C" void kernel_launch(void* const* d_in, const int* in_sizes, int n_in,
                              void* d_out, int out_size, void* d_ws, size_t ws_size,
                              hipStream_t stream)
{
    const float* x    = (const float*)d_in[0];
    const int*   pidx = (const int*)d_in[1];
    const float* W1   = (const float*)d_in[2];
    const float* b1   = (const float*)d_in[3];
    const float* g1   = (const float*)d_in[4];
    const float* be1  = (const float*)d_in[5];
    const float* W2   = (const float*)d_in[6];
    const float* b2   = (const float*)d_in[7];
    const float* g2   = (const float*)d_in[8];
    const float* be2  = (const float*)d_in[9];
    const float* Wr1  = (const float*)d_in[10];
    const float* br1  = (const float*)d_in[11];
    const float* gr1  = (const float*)d_in[12];
    const float* ber1 = (const float*)d_in[13];
    const float* Wr2  = (const float*)d_in[14];
    const float* br2  = (const float*)d_in[15];
    float* out = (float*)d_out;

    // workspace: h2 (bf16, 64 MiB) | rbuf (fp32, ~1 MiB)
    unsigned short* h2 = (unsigned short*)d_ws;
    float* rbuf = (float*)(h2 + (size_t)MROWS * NF);

    fused12_kernel<<<1024, 256, 0, stream>>>(x, W1, b1, g1, be1,
                                             W2, b2, g2, be2, h2);
    edge_kernel<<<1024, 256, 0, stream>>>(h2, pidx, Wr1, br1, gr1, ber1,
                                          Wr2, br2, rbuf);
    lse_kernel<<<BATCH, 256, 0, stream>>>(rbuf, out);
}

// Round 4
// 346.354 us; speedup vs baseline: 1.9743x; 1.9743x over previous
//
#include <hip/hip_runtime.h>

#define NF     128
#define BATCH  64
#define NNODES 4096
#define MROWS  (BATCH * NNODES)       // 262144
#define NEDGE  (BATCH * (NNODES - 1)) // 262080
#define LN_EPS 1e-5f
#define AP     136                    // padded stride (shorts); 272 B = 17*16 B, keeps b128 alignment

typedef short  short8  __attribute__((ext_vector_type(8)));
typedef short  short4v __attribute__((ext_vector_type(4)));
typedef float  float4v __attribute__((ext_vector_type(4)));

__device__ __forceinline__ unsigned short f2bf(float f) {
    union { float f; unsigned u; } v; v.f = f;
    unsigned r = v.u;
    r = r + 0x7FFF + ((r >> 16) & 1);   // RNE
    return (unsigned short)(r >> 16);
}
__device__ __forceinline__ float bf2f(unsigned short b) {
    union { unsigned u; float f; } v; v.u = ((unsigned)b) << 16;
    return v.f;
}

// A-fragment slot address (in shorts) inside a wave's 4-KB frag region.
// slot(q,m) holds A[m][q*8 .. q*8+7] as 8 bf16 (16 B). XOR-swizzle by q&7
// spreads same-m writes across bank groups (edge writer would otherwise be
// 16-way conflicted). Writers and readers both use this function.
__device__ __forceinline__ int slotAddr(int q, int m) {
    return ((q * 16 + m) ^ (q & 7)) * 8;
}

// In-place bias + LayerNorm(128) + ELU on the C-layout accumulator.
// acc[c][r] holds (row = qu*4+r, col = c*16+lnm); a row's 128 cols live in
// 16 lanes (fixed qu) -> shfl_xor width 16.
__device__ __forceinline__ void ln_elu(float4v acc[8], const float* __restrict__ P,
                                       int lnm) {
    float bias[8], gn[8], bt[8];
    #pragma unroll
    for (int c = 0; c < 8; ++c) {
        int n = c * 16 + lnm;
        bias[c] = P[n]; gn[c] = P[NF + n]; bt[c] = P[2 * NF + n];
    }
    #pragma unroll
    for (int r = 0; r < 4; ++r) {
        float s1 = 0.f, s2 = 0.f;
        #pragma unroll
        for (int c = 0; c < 8; ++c) {
            float t = acc[c][r] + bias[c];
            acc[c][r] = t;
            s1 += t; s2 += t * t;
        }
        #pragma unroll
        for (int m = 1; m < 16; m <<= 1) {
            s1 += __shfl_xor(s1, m, 16);
            s2 += __shfl_xor(s2, m, 16);
        }
        float mu  = s1 * (1.0f / 128.0f);
        float var = s2 * (1.0f / 128.0f) - mu * mu;
        float rs  = rsqrtf(var + LN_EPS);
        #pragma unroll
        for (int c = 0; c < 8; ++c) {
            float y = (acc[c][r] - mu) * rs * gn[c] + bt[c];
            acc[c][r] = (y > 0.f) ? y : (__expf(y) - 1.0f);
        }
    }
}

// Stage W (fp32, k-major) -> B-fragment registers, transposing through SH in
// 32-column chunks (needs 32*AP = 8704 B of SH; setup-only). Coalesced reads.
__device__ __forceinline__ void load_wfrags(const float* __restrict__ W,
                                            unsigned short* __restrict__ SH,
                                            int tid, int lnm, int qu,
                                            short8 frag[8][4]) {
    for (int ch = 0; ch < 4; ++ch) {
        __syncthreads();
        #pragma unroll
        for (int i = 0; i < 16; ++i) {
            int flat = tid + 256 * i;     // 0..4095
            int k = flat >> 5;            // 0..127
            int j = flat & 31;            // local n
            SH[j * AP + k] = f2bf(W[k * NF + ch * 32 + j]);
        }
        __syncthreads();
        #pragma unroll
        for (int cc = 0; cc < 2; ++cc) {
            int c = ch * 2 + cc;
            #pragma unroll
            for (int s = 0; s < 4; ++s)
                frag[c][s] = *(const short8*)&SH[(cc * 16 + lnm) * AP + s * 32 + qu * 8];
        }
    }
}

// Fused layer1+layer2: x (fp32) -> LN/ELU(xW1) -> LN/ELU(h1 W2) -> h2 (bf16).
// Per-wave 16-row strips, no main-loop barriers, coalesced global I/O,
// register prefetch of strip i+1.
__global__ __launch_bounds__(256)
void fused12_kernel(const float* __restrict__ x,
                    const float* __restrict__ W1, const float* __restrict__ b1,
                    const float* __restrict__ g1, const float* __restrict__ be1,
                    const float* __restrict__ W2, const float* __restrict__ b2,
                    const float* __restrict__ g2, const float* __restrict__ be2,
                    unsigned short* __restrict__ h2out)
{
    __shared__ __align__(16) unsigned short SH[4 * 2176];  // 17408 B: wave frag bufs / W staging
    __shared__ float P[6 * NF];

    const int tid  = threadIdx.x;
    const int lane = tid & 63;
    const int wave = tid >> 6;
    const int lnm  = lane & 15;
    const int qu   = lane >> 4;

    if (tid < NF) {
        P[tid]          = b1[tid]; P[NF + tid]     = g1[tid]; P[2 * NF + tid] = be1[tid];
        P[3 * NF + tid] = b2[tid]; P[4 * NF + tid] = g2[tid]; P[5 * NF + tid] = be2[tid];
    }
    short8 bf1[8][4], bf2[8][4];
    load_wfrags(W1, SH, tid, lnm, qu, bf1);
    load_wfrags(W2, SH, tid, lnm, qu, bf2);

    unsigned short* myF = &SH[wave * 2176];
    const int nstrips = MROWS / 16;       // 16384
    const int sstep   = gridDim.x * 4;
    int strip = blockIdx.x * 4 + wave;

    // prefetch strip 0: 8 x 16-B coalesced (1 KiB/instr, strip is 8 KB contiguous)
    float4v rx[8];
    if (strip < nstrips) {
        const float* xs = x + (size_t)strip * (16 * NF);
        #pragma unroll
        for (int t = 0; t < 8; ++t)
            rx[t] = *(const float4v*)(xs + t * 256 + lane * 4);
    }
    __syncthreads();   // frag reads done; SH now per-wave

    const int qx = (lane & 31) >> 1;   // k-octet this lane's x chunk falls in
    const int hx = (lane & 1) * 4;     // half-slot offset (shorts)

    for (; strip < nstrips; strip += sstep) {
        // rx -> A slots (lane holds rows t*2+(lane>>5), cols (lane&31)*4..+3)
        #pragma unroll
        for (int t = 0; t < 8; ++t) {
            int m = t * 2 + (lane >> 5);
            union { short4v v; unsigned short e[4]; } u;
            u.e[0] = f2bf(rx[t][0]); u.e[1] = f2bf(rx[t][1]);
            u.e[2] = f2bf(rx[t][2]); u.e[3] = f2bf(rx[t][3]);
            *(short4v*)&myF[slotAddr(qx, m) + hx] = u.v;
        }
        // prefetch strip i+1 (in flight through all of compute below)
        int sn = strip + sstep;
        if (sn < nstrips) {
            const float* xs = x + (size_t)sn * (16 * NF);
            #pragma unroll
            for (int t = 0; t < 8; ++t)
                rx[t] = *(const float4v*)(xs + t * 256 + lane * 4);
        }

        // layer 1
        float4v acc[8];
        #pragma unroll
        for (int c = 0; c < 8; ++c) acc[c] = (float4v){0.f, 0.f, 0.f, 0.f};
        #pragma unroll
        for (int s = 0; s < 4; ++s) {
            short8 af = *(const short8*)&myF[slotAddr(s * 4 + qu, lnm)];
            #pragma unroll
            for (int c = 0; c < 8; ++c)
                acc[c] = __builtin_amdgcn_mfma_f32_16x16x32_bf16(af, bf1[c][s], acc[c], 0, 0, 0);
        }
        ln_elu(acc, &P[0], lnm);

        // repack h1 (C layout) -> A slots for layer 2 (in-wave, DS in-order)
        #pragma unroll
        for (int c = 0; c < 8; ++c) {
            int qq = c * 2 + (lnm >> 3), j = lnm & 7;
            #pragma unroll
            for (int r = 0; r < 4; ++r)
                myF[slotAddr(qq, qu * 4 + r) + j] = f2bf(acc[c][r]);
        }

        // layer 2
        #pragma unroll
        for (int c = 0; c < 8; ++c) acc[c] = (float4v){0.f, 0.f, 0.f, 0.f};
        #pragma unroll
        for (int s = 0; s < 4; ++s) {
            short8 af = *(const short8*)&myF[slotAddr(s * 4 + qu, lnm)];
            #pragma unroll
            for (int c = 0; c < 8; ++c)
                acc[c] = __builtin_amdgcn_mfma_f32_16x16x32_bf16(af, bf2[c][s], acc[c], 0, 0, 0);
        }
        ln_elu(acc, &P[3 * NF], lnm);

        // out-repack (row-major, padded) then coalesced 1-KiB stores
        #pragma unroll
        for (int c = 0; c < 8; ++c)
            #pragma unroll
            for (int r = 0; r < 4; ++r)
                myF[(qu * 4 + r) * AP + c * 16 + lnm] = f2bf(acc[c][r]);

        unsigned short* ob = h2out + (size_t)strip * (16 * NF);
        #pragma unroll
        for (int t = 0; t < 4; ++t) {
            int row = t * 4 + (lane >> 4);
            short8 pk = *(const short8*)&myF[row * AP + (lane & 15) * 8];
            *(short8*)(ob + t * 512 + lane * 8) = pk;
        }
    }
}

// Edge kernel: e = max(h2[child], h2[parent]) -> LN/ELU(e Wr1) -> dot Wr2 + br2.
// 16 lanes cover one full 256-B row per gather (coalesced at row granularity);
// rows prefetched one strip ahead, pidx two ahead.
__global__ __launch_bounds__(256)
void edge_kernel(const unsigned short* __restrict__ h2,
                 const int* __restrict__ pidx,
                 const float* __restrict__ Wr1, const float* __restrict__ br1,
                 const float* __restrict__ gr1, const float* __restrict__ ber1,
                 const float* __restrict__ Wr2, const float* __restrict__ br2,
                 float* __restrict__ rout)
{
    __shared__ __align__(16) unsigned short SH[4 * 2176];
    __shared__ float P[3 * NF];

    const int tid  = threadIdx.x;
    const int lane = tid & 63;
    const int wave = tid >> 6;
    const int lnm  = lane & 15;
    const int qu   = lane >> 4;

    if (tid < NF) { P[tid] = br1[tid]; P[NF + tid] = gr1[tid]; P[2 * NF + tid] = ber1[tid]; }
    short8 bfr[8][4];
    load_wfrags(Wr1, SH, tid, lnm, qu, bfr);

    float w2c[8];
    #pragma unroll
    for (int c = 0; c < 8; ++c) w2c[c] = Wr2[c * 16 + lnm];
    const float br2v = br2[0];

    unsigned short* myF = &SH[wave * 2176];
    const int nstrips = NEDGE / 16;       // 16380
    const int sstep   = gridDim.x * 4;
    const int s0      = blockIdx.x * 4 + wave;

    short8 cv[4], pv[4];
    int prn[4];
    if (s0 < nstrips) {
        int pr[4];
        #pragma unroll
        for (int t = 0; t < 4; ++t) pr[t] = pidx[s0 * 16 + t * 4 + qu];
        #pragma unroll
        for (int t = 0; t < 4; ++t) {
            int e = s0 * 16 + t * 4 + qu;
            int crow = e + (int)((unsigned)e / 4095u);
            cv[t] = *(const short8*)(h2 + (size_t)crow * NF + lnm * 8);
            pv[t] = *(const short8*)(h2 + (size_t)pr[t] * NF + lnm * 8);
        }
        int s1 = s0 + sstep;
        if (s1 < nstrips) {
            #pragma unroll
            for (int t = 0; t < 4; ++t) prn[t] = pidx[s1 * 16 + t * 4 + qu];
        }
    }
    __syncthreads();

    for (int strip = s0; strip < nstrips; strip += sstep) {
        // max + convert -> A slots (edge m = t*4+qu, k = lnm*8..+7 -> one full slot)
        #pragma unroll
        for (int t = 0; t < 4; ++t) {
            union { short8 v; unsigned short e8[8]; } u;
            #pragma unroll
            for (int j = 0; j < 8; ++j)
                u.e8[j] = f2bf(fmaxf(bf2f((unsigned short)cv[t][j]),
                                     bf2f((unsigned short)pv[t][j])));
            *(short8*)&myF[slotAddr(lnm, t * 4 + qu)] = u.v;
        }

        // prefetch rows for strip+sstep (pidx already in prn), pidx for +2*sstep
        int sn = strip + sstep;
        if (sn < nstrips) {
            #pragma unroll
            for (int t = 0; t < 4; ++t) {
                int e = sn * 16 + t * 4 + qu;
                int crow = e + (int)((unsigned)e / 4095u);
                cv[t] = *(const short8*)(h2 + (size_t)crow * NF + lnm * 8);
                pv[t] = *(const short8*)(h2 + (size_t)prn[t] * NF + lnm * 8);
            }
            int sn2 = sn + sstep;
            if (sn2 < nstrips) {
                #pragma unroll
                for (int t = 0; t < 4; ++t) prn[t] = pidx[sn2 * 16 + t * 4 + qu];
            }
        }

        // MFMA + LN/ELU + dot
        float4v acc[8];
        #pragma unroll
        for (int c = 0; c < 8; ++c) acc[c] = (float4v){0.f, 0.f, 0.f, 0.f};
        #pragma unroll
        for (int s = 0; s < 4; ++s) {
            short8 af = *(const short8*)&myF[slotAddr(s * 4 + qu, lnm)];
            #pragma unroll
            for (int c = 0; c < 8; ++c)
                acc[c] = __builtin_amdgcn_mfma_f32_16x16x32_bf16(af, bfr[c][s], acc[c], 0, 0, 0);
        }
        ln_elu(acc, P, lnm);

        #pragma unroll
        for (int r = 0; r < 4; ++r) {
            float t2 = 0.f;
            #pragma unroll
            for (int c = 0; c < 8; ++c) t2 += acc[c][r] * w2c[c];
            #pragma unroll
            for (int m = 1; m < 16; m <<= 1) t2 += __shfl_xor(t2, m, 16);
            if (lnm == 0) rout[strip * 16 + qu * 4 + r] = t2 + br2v;
        }
    }
}

__global__ __launch_bounds__(256)
void lse_kernel(const float* __restrict__ r, float* __restrict__ out)
{
    __shared__ float red[256];
    const int b = blockIdx.x;
    const float* rb = r + (size_t)b * 4095;

    float mx = -1e30f;
    for (int i = threadIdx.x; i < 4095; i += 256) mx = fmaxf(mx, rb[i]);
    red[threadIdx.x] = mx;
    __syncthreads();
    for (int s = 128; s > 0; s >>= 1) {
        if (threadIdx.x < s) red[threadIdx.x] = fmaxf(red[threadIdx.x], red[threadIdx.x + s]);
        __syncthreads();
    }
    mx = red[0];
    __syncthreads();

    float sum = 0.f;
    for (int i = threadIdx.x; i < 4095; i += 256) sum += __expf(rb[i] - mx);
    red[threadIdx.x] = sum;
    __syncthreads();
    for (int s = 128; s > 0; s >>= 1) {
        if (threadIdx.x < s) red[threadIdx.x] += red[threadIdx.x + s];
        __syncthreads();
    }
    float lse = mx + __logf(red[0]);

    for (int i = threadIdx.x; i < 4095; i += 256)
        out[(size_t)b * 4095 + i] = rb[i] - lse;
}

extern "C" void kernel_launch(void* const* d_in, const int* in_sizes, int n_in,
                              void* d_out, int out_size, void* d_ws, size_t ws_size,
                              hipStream_t stream)
{
    const float* x    = (const float*)d_in[0];
    const int*   pidx = (const int*)d_in[1];
    const float* W1   = (const float*)d_in[2];
    const float* b1   = (const float*)d_in[3];
    const float* g1   = (const float*)d_in[4];
    const float* be1  = (const float*)d_in[5];
    const float* W2   = (const float*)d_in[6];
    const float* b2   = (const float*)d_in[7];
    const float* g2   = (const float*)d_in[8];
    const float* be2  = (const float*)d_in[9];
    const float* Wr1  = (const float*)d_in[10];
    const float* br1  = (const float*)d_in[11];
    const float* gr1  = (const float*)d_in[12];
    const float* ber1 = (const float*)d_in[13];
    const float* Wr2  = (const float*)d_in[14];
    const float* br2  = (const float*)d_in[15];
    float* out = (float*)d_out;

    // workspace: h2 (bf16, 64 MiB) | rbuf (fp32, ~1 MiB)
    unsigned short* h2 = (unsigned short*)d_ws;
    float* rbuf = (float*)(h2 + (size_t)MROWS * NF);

    fused12_kernel<<<1024, 256, 0, stream>>>(x, W1, b1, g1, be1,
                                             W2, b2, g2, be2, h2);
    edge_kernel<<<1024, 256, 0, stream>>>(h2, pidx, Wr1, br1, gr1, ber1,
                                          Wr2, br2, rbuf);
    lse_kernel<<<BATCH, 256, 0, stream>>>(rbuf, out);
}